// Round 1
// baseline (155.988 us; speedup 1.0000x reference)
//
#include <hip/hip_runtime.h>

#define EG   16000   // graph edges
#define NG   1000    // graph_size (block rows/cols)
#define BB   32      // batch
#define SIZE 16000   // feature length (NG*16)

// ---- binning pipeline: bucket edges by destination block-row t0 ----

__global__ void count_kernel(const int* __restrict__ rows, int* __restrict__ cnt) {
    int e = blockIdx.x * blockDim.x + threadIdx.x;
    if (e < EG) {
        int t0 = rows[e << 8] >> 4;   // rows[e*256] = t0*16 + 0
        atomicAdd(&cnt[t0], 1);
    }
}

__global__ void scan_kernel(const int* __restrict__ cnt,
                            int* __restrict__ bin_start,
                            int* __restrict__ cursor) {
    __shared__ int s[1024];
    int t = threadIdx.x;
    int c = (t < NG) ? cnt[t] : 0;
    s[t] = c;
    __syncthreads();
    for (int off = 1; off < 1024; off <<= 1) {
        int v = (t >= off) ? s[t - off] : 0;
        __syncthreads();
        s[t] += v;
        __syncthreads();
    }
    int incl = s[t];                  // inclusive scan
    if (t < NG) { bin_start[t] = incl - c; cursor[t] = incl - c; }
    if (t == 1023) bin_start[NG] = incl;   // total = EG
}

__global__ void scatter_kernel(const int* __restrict__ rows,
                               int* __restrict__ cursor,
                               int* __restrict__ edge_of) {
    int e = blockIdx.x * blockDim.x + threadIdx.x;
    if (e < EG) {
        int t0 = rows[e << 8] >> 4;
        int pos = atomicAdd(&cursor[t0], 1);
        edge_of[pos] = e;
    }
}

// ---- main kernel: one workgroup per destination block-row ----
// Thread t owns output elements (b0, j) and (b0+16, j), j = t&15, b0 = t>>4.
// Per edge: stage 256 sampled weights + 512 x values in LDS, 32 FMAs/thread.

__global__ __launch_bounds__(256) void spmm_kernel(
    const float* __restrict__ wm, const float* __restrict__ wlv,
    const float* __restrict__ ew, const float* __restrict__ x,
    const float* __restrict__ bm, const float* __restrict__ blv,
    const float* __restrict__ eb, const int* __restrict__ cols,
    const int* __restrict__ edge_of, const int* __restrict__ bin_start,
    float* __restrict__ out)
{
    __shared__ float vt[256];   // vt[i*16+j] = sampled weight
    __shared__ float xs[512];   // xs[b*16+i] = x[b, t1*16+i]

    int g   = blockIdx.x;
    int tid = threadIdx.x;
    int j   = tid & 15;
    int b0  = tid >> 4;          // 0..15

    float acc0 = 0.f, acc1 = 0.f;
    int start = bin_start[g], end = bin_start[g + 1];

    for (int p = start; p < end; ++p) {
        int e    = edge_of[p];
        int base = e << 8;
        int t1   = cols[base] >> 4;          // cols[e*256] = t1*16 + 0
        // values = eps_w * exp(log_var) + mean  (reparameterization sample)
        vt[tid] = ew[base + tid] * __expf(wlv[base + tid]) + wm[base + tid];
        int xb = t1 << 4;
        xs[tid]       = x[ b0        * SIZE + xb + j];   // (b0, i=j slot)
        xs[tid + 256] = x[(b0 + 16)  * SIZE + xb + j];
        __syncthreads();
        #pragma unroll
        for (int i = 0; i < 16; ++i) {
            float vv = vt[(i << 4) + j];
            acc0 += vv * xs[((b0)      << 4) + i];
            acc1 += vv * xs[((b0 + 16) << 4) + i];
        }
        __syncthreads();
    }

    int r = (g << 4) + j;
    float bias = eb[r] * __expf(blv[r]) + bm[r];
    out[ b0       * SIZE + r] = acc0 + bias;
    out[(b0 + 16) * SIZE + r] = acc1 + bias;
    if (g == 0 && tid == 0) out[BB * SIZE] = 0.0f;  // kl scalar
}

extern "C" void kernel_launch(void* const* d_in, const int* in_sizes, int n_in,
                              void* d_out, int out_size, void* d_ws, size_t ws_size,
                              hipStream_t stream) {
    const float* x   = (const float*)d_in[0];
    const float* wm  = (const float*)d_in[1];
    const float* wlv = (const float*)d_in[2];
    const float* bm  = (const float*)d_in[3];
    const float* blv = (const float*)d_in[4];
    const float* ew  = (const float*)d_in[5];
    const float* eb  = (const float*)d_in[6];
    const int* rows  = (const int*)d_in[7];
    const int* cols  = (const int*)d_in[8];
    float* out = (float*)d_out;

    char* ws = (char*)d_ws;
    int* cnt       = (int*)(ws);              // 1024 ints
    int* bin_start = (int*)(ws + 4096);       // 1001 ints
    int* cursor    = (int*)(ws + 8192);       // 1000 ints
    int* edge_of   = (int*)(ws + 12288);      // 16000 ints

    hipMemsetAsync(cnt, 0, 4096, stream);
    count_kernel<<<(EG + 255) / 256, 256, 0, stream>>>(rows, cnt);
    scan_kernel<<<1, 1024, 0, stream>>>(cnt, bin_start, cursor);
    scatter_kernel<<<(EG + 255) / 256, 256, 0, stream>>>(rows, cursor, edge_of);
    spmm_kernel<<<NG, 256, 0, stream>>>(wm, wlv, ew, x, bm, blv, eb, cols,
                                        edge_of, bin_start, out);
}